// Round 8
// baseline (1011.223 us; speedup 1.0000x reference)
//
#include <hip/hip_runtime.h>

typedef unsigned short u16;
typedef short bf8 __attribute__((ext_vector_type(8)));
typedef float f4 __attribute__((ext_vector_type(4)));
typedef _Float16 h2v __attribute__((ext_vector_type(2)));
typedef __fp16 g2v __attribute__((ext_vector_type(2)));
typedef unsigned int u4v __attribute__((ext_vector_type(4)));

#define N_NODES 20000
#define N_EDGES 320000
#define NGRAPH 40
#define NPG 500
#define KTOP 250
#define NSEG (N_NODES * 8)

// parms arena offsets (u16 elements)
#define P_CONV_BIAS 0
#define P_POOL_W    768
#define P_POOL_ROOT 6912
#define P_POOL_BIAS 7680
#define P_FC1_W     7688
#define P_FC1_B     204296
#define P_W_IH      204552
#define P_B_IH      466696
#define P_B_HH      467720
#define P_FC2_W     468744
#define P_FC2_B     469256
#define P_TOTAL     469264

__device__ __forceinline__ float b2f(u16 u) {
    union { unsigned int i; float f; } v; v.i = ((unsigned int)u) << 16; return v.f;
}
__device__ __forceinline__ u16 f2b(float f) {
    union { float f; unsigned int i; } v; v.f = f;
    unsigned int x = v.i;
    return (u16)((x + 0x7fffu + ((x >> 16) & 1u)) >> 16);
}
__device__ __forceinline__ float wred(float s) {
    #pragma unroll
    for (int off = 32; off > 0; off >>= 1) s += __shfl_down(s, off);
    return s;
}
__device__ __forceinline__ float fdot2u(unsigned a, unsigned b, float c) {
#if __has_builtin(__builtin_amdgcn_fdot2)
    union { unsigned u; h2v h; } ua, ub; ua.u = a; ub.u = b;
    return __builtin_amdgcn_fdot2(ua.h, ub.h, c, false);
#else
    union { unsigned u; g2v h; } ua, ub; ua.u = a; ub.u = b;
    return c + (float)ua.h[0] * (float)ub.h[0] + (float)ua.h[1] * (float)ub.h[1];
#endif
}
__device__ __forceinline__ unsigned packh2(float a, float b) {
    g2v h = __builtin_amdgcn_cvt_pkrtz(a, b);
    union { g2v h; unsigned u; } v; v.h = h; return v.u;
}

// ---------------- init: zero flag + cnt + ctr ----------------
__global__ void k_init(unsigned int* __restrict__ flag, unsigned int* __restrict__ cnt,
                       unsigned int* __restrict__ ctr) {
    int i = blockIdx.x * 256 + threadIdx.x;
    if (i < 64) flag[i] = 0u;
    if (i < NSEG) { cnt[i] = 0u; ctr[i] = 0u; }
}

// ---------------- dtype detection (parallel) ----------------
__global__ void k_detect1(const u16* __restrict__ xr, int n, unsigned int* __restrict__ fb) {
    unsigned int local = 0;
    for (int i = blockIdx.x * 256 + threadIdx.x; i < n; i += 64 * 256) {
        unsigned int u = xr[i];
        if (((u >> 7) & 0xFFu) == 0xFFu) local++;
    }
    local = (unsigned int)wred((float)local);
    if ((threadIdx.x & 63) == 0 && local) atomicAdd(&fb[1], local);
}
__global__ void k_detect2(unsigned int* __restrict__ fb) {
    fb[0] = (fb[1] > 8u) ? 1u : 0u;
}

__device__ __forceinline__ u16 load_cvt(const void* src, size_t i, bool f32) {
    return f32 ? f2b(((const float*)src)[i]) : ((const u16*)src)[i];
}

// ---------------- one-shot param canonicalization ----------------
__global__ void k_cvt_all(const void* conv_bias, const void* pool_W, const void* pool_root,
                          const void* pool_bias, const void* fc1_W, const void* fc1_b,
                          const void* W_ih, const void* b_ih, const void* b_hh,
                          const void* fc2_W, const void* fc2_b,
                          u16* __restrict__ parms, const unsigned int* __restrict__ flag) {
    int i = blockIdx.x * 256 + threadIdx.x;
    if (i >= P_TOTAL) return;
    bool f32 = (*flag != 0u);
    u16 v;
    if      (i < P_CONV_BIAS + 768)    v = load_cvt(conv_bias, i - P_CONV_BIAS, f32);
    else if (i < P_POOL_W + 6144)      v = load_cvt(pool_W,    i - P_POOL_W, f32);
    else if (i < P_POOL_ROOT + 768)    v = load_cvt(pool_root, i - P_POOL_ROOT, f32);
    else if (i < P_POOL_BIAS + 1)      v = load_cvt(pool_bias, i - P_POOL_BIAS, f32);
    else if (i < P_FC1_W && i >= P_POOL_BIAS) return;        // alignment gap
    else if (i < P_FC1_W + 196608)     v = load_cvt(fc1_W,    i - P_FC1_W, f32);
    else if (i < P_FC1_B + 256)        v = load_cvt(fc1_b,    i - P_FC1_B, f32);
    else if (i < P_W_IH + 262144)      v = load_cvt(W_ih,     i - P_W_IH, f32);
    else if (i < P_B_IH + 1024)        v = load_cvt(b_ih,     i - P_B_IH, f32);
    else if (i < P_B_HH + 1024)        v = load_cvt(b_hh,     i - P_B_HH, f32);
    else if (i < P_FC2_W + 512)        v = load_cvt(fc2_W,    i - P_FC2_W, f32);
    else if (i < P_FC2_B + 2)          v = load_cvt(fc2_b,    i - P_FC2_B, f32);
    else return;
    parms[i] = v;
}

// stage x (canonical bf16) into xc[:, 512:768]
__global__ void k_stage_x(const void* __restrict__ src, u16* __restrict__ xc,
                          const unsigned int* __restrict__ flag) {
    int i = blockIdx.x * 256 + threadIdx.x;
    if (i >= N_NODES * 256) return;
    u16 v = load_cvt(src, i, *flag != 0u);
    int n = i >> 8, f = i & 255;
    xc[(size_t)n * 768 + 512 + f] = v;
}

// ---------------- degree counts ----------------
__global__ void k_count(const int* __restrict__ dst, const int* __restrict__ et,
                        unsigned int* __restrict__ cnt) {
    int e = blockIdx.x * 256 + threadIdx.x;
    if (e < N_EDGES) {
        unsigned d = (unsigned)dst[e]; if (d >= N_NODES) d = 0;
        unsigned r = (unsigned)et[e] & 7u;
        atomicAdd(&cnt[d * 8 + r], 1u);
    }
}
__global__ void k_inv(const unsigned int* __restrict__ cnt, float* __restrict__ inv, int n) {
    int i = blockIdx.x * 256 + threadIdx.x;
    if (i < n) {
        unsigned int c = cnt[i];
        inv[i] = 1.0f / (float)(c < 1u ? 1u : c);
    }
}

// ---------------- prefix scan (exclusive) over cnt[160000] ----------------
__global__ void k_scan1(const unsigned int* __restrict__ cnt, unsigned int* __restrict__ seg,
                        unsigned int* __restrict__ bsum) {
    __shared__ unsigned int s[256];
    int t = threadIdx.x, i = blockIdx.x * 256 + t;
    unsigned int v = (i < NSEG) ? cnt[i] : 0u;
    s[t] = v;
    __syncthreads();
    for (int off = 1; off < 256; off <<= 1) {
        unsigned int add = (t >= off) ? s[t - off] : 0u;
        __syncthreads();
        s[t] += add;
        __syncthreads();
    }
    if (i < NSEG) seg[i] = s[t] - v;
    if (t == 255) bsum[blockIdx.x] = s[255];
}
__global__ void k_scan2(unsigned int* __restrict__ bsum, int nb) {
    __shared__ unsigned int s[1024];
    int t = threadIdx.x;
    unsigned int v = (t < nb) ? bsum[t] : 0u;
    s[t] = v;
    __syncthreads();
    for (int off = 1; off < 1024; off <<= 1) {
        unsigned int add = (t >= off) ? s[t - off] : 0u;
        __syncthreads();
        s[t] += add;
        __syncthreads();
    }
    if (t < nb) bsum[t] = s[t] - v;
}
__global__ void k_scan3(unsigned int* __restrict__ seg, const unsigned int* __restrict__ bsum) {
    int i = blockIdx.x * 256 + threadIdx.x;
    if (i < NSEG) seg[i] += bsum[i >> 8];
    if (i == 0) seg[NSEG] = N_EDGES;
}
// place edges into (dst,rel)-sorted order; skey = src node id
__global__ void k_place(const int* __restrict__ src, const int* __restrict__ dst,
                        const int* __restrict__ et, const unsigned int* __restrict__ seg,
                        unsigned int* __restrict__ ctr, const float* __restrict__ inv,
                        unsigned int* __restrict__ skey, float* __restrict__ sw) {
    int e = blockIdx.x * 256 + threadIdx.x;
    if (e >= N_EDGES) return;
    unsigned s = (unsigned)src[e]; if (s >= N_NODES) s = 0;
    unsigned d = (unsigned)dst[e]; if (d >= N_NODES) d = 0;
    unsigned r = (unsigned)et[e] & 7u;
    unsigned key = d * 8 + r;
    unsigned pos = seg[key] + atomicAdd(&ctr[key], 1u);
    skey[pos] = s;
    sw[pos] = inv[key];
}

// ---------------- weight prep: chunked Wt [l][ck=36][n=256][kk=64] ----------------
// global k = ck*64+kk; k<2048 -> conv_W[l][k>>8][k&255][n]; k>=2048 -> conv_root[l][k-2048][n]
__global__ void k_transpose2(const void* __restrict__ conv_W, const void* __restrict__ conv_root,
                             u16* __restrict__ Wt, const unsigned int* __restrict__ flag) {
    int idx = blockIdx.x * 256 + threadIdx.x;
    if (idx >= 3 * 36 * 256 * 64) return;
    bool f32 = (*flag != 0u);
    int kk = idx & 63;
    int n = (idx >> 6) & 255;
    int lc = idx >> 14;            // l*36 + ck
    int l = lc / 36, ck = lc % 36;
    int k = ck * 64 + kk;
    u16 v;
    if (k < 2048) {
        int r = k >> 8, i = k & 255;
        v = load_cvt(conv_W, ((size_t)((l * 8 + r) * 256 + i)) * 256 + n, f32);
    } else {
        int i = k - 2048;
        v = load_cvt(conv_root, ((size_t)(l * 256 + i)) * 256 + n, f32);
    }
    Wt[idx] = v;
}
// W_hh [j][i] -> whh4[i4][j][4] packed f16 pairs (i2 = i4*4+c, pair = (2*i2, 2*i2+1))
__global__ void k_whh4(const void* __restrict__ W_hh, unsigned int* __restrict__ whh4,
                       const unsigned int* __restrict__ flag) {
    int idx = blockIdx.x * 256 + threadIdx.x;     // 32*1024*4
    if (idx >= 32 * 1024 * 4) return;
    int c = idx & 3, j = (idx >> 2) & 1023, i4 = idx >> 12;
    int i2 = i4 * 4 + c;
    bool f32 = (*flag != 0u);
    float a, b;
    if (f32) {
        a = ((const float*)W_hh)[j * 256 + 2 * i2];
        b = ((const float*)W_hh)[j * 256 + 2 * i2 + 1];
    } else {
        a = b2f(((const u16*)W_hh)[j * 256 + 2 * i2]);
        b = b2f(((const u16*)W_hh)[j * 256 + 2 * i2 + 1]);
    }
    whh4[idx] = packh2(a, b);
}

// ---------------- fused RGCN layer: gather + GEMM + bias + relu + store ----------------
// grid 625 blocks (32 dst rows each), 256 threads. Wave w: M rows (w&1)*16..+15,
// N cols (w>>1)*128..+127. Per rel: gather 32 mean-aggregated rows into LDS As, then
// 4 x 64-k chunks of B (chunk-contiguous layout) via LDS Bs, MFMA accumulate.
// rel 8 = root (identity rows from xprev, chunks 32..35).
__launch_bounds__(256, 2)
__global__ void k_layer(const unsigned int* __restrict__ seg,
                        const unsigned int* __restrict__ skey,
                        const float* __restrict__ sw,
                        const u16* __restrict__ xprev,      // stride 768
                        const u16* __restrict__ WtL,        // [36][256][64]
                        const u16* __restrict__ bias,
                        u16* __restrict__ xc, int colbase) {
    __shared__ u16 As[32 * 264];
    __shared__ u16 Bs[256 * 72];
    int wave = threadIdx.x >> 6, lane = threadIdx.x & 63;
    int m0 = blockIdx.x * 32;
    int mrow = lane & 15, quad = lane >> 4;
    int arow = (wave & 1) * 16 + mrow;
    int nbase = (wave >> 1) * 128;

    f4 acc[8];
    #pragma unroll
    for (int nt = 0; nt < 8; ++nt) acc[nt] = (f4){0.0f, 0.0f, 0.0f, 0.0f};

    for (int rg = 0; rg < 9; ++rg) {
        __syncthreads();                       // As safe to overwrite
        // gather: wave w fills rows w*8 .. w*8+7; lane covers cols lane*4..+3
        #pragma unroll 2
        for (int j = 0; j < 8; ++j) {
            int row = wave * 8 + j;
            int m = m0 + row;
            ushort4 o;
            if (rg < 8) {
                unsigned nb = seg[m * 8 + rg], ne = seg[m * 8 + rg + 1];
                float a0 = 0.0f, a1 = 0.0f, a2 = 0.0f, a3 = 0.0f;
                for (unsigned i = nb; i < ne; ++i) {
                    float wgt = sw[i];
                    ushort4 u = *(const ushort4*)(xprev + (size_t)skey[i] * 768 + lane * 4);
                    a0 += wgt * b2f(u.x); a1 += wgt * b2f(u.y);
                    a2 += wgt * b2f(u.z); a3 += wgt * b2f(u.w);
                }
                o.x = f2b(a0); o.y = f2b(a1); o.z = f2b(a2); o.w = f2b(a3);
            } else {
                o = *(const ushort4*)(xprev + (size_t)m * 768 + lane * 4);
            }
            *(ushort4*)(As + row * 264 + lane * 4) = o;
        }
        #pragma unroll
        for (int c4 = 0; c4 < 4; ++c4) {
            int ck = rg * 4 + c4;
            __syncthreads();                   // Bs safe + As gather visible
            {
                const u16* srcp = WtL + (size_t)ck * 16384 + threadIdx.x * 64;
                u16* dstp = Bs + threadIdx.x * 72;
                #pragma unroll
                for (int c = 0; c < 8; ++c)
                    *(bf8*)(dstp + c * 8) = *(const bf8*)(srcp + c * 8);
            }
            __syncthreads();
            #pragma unroll
            for (int ks = 0; ks < 2; ++ks) {
                bf8 a = *(const bf8*)(As + arow * 264 + c4 * 64 + ks * 32 + quad * 8);
                #pragma unroll
                for (int nt = 0; nt < 8; ++nt) {
                    bf8 b = *(const bf8*)(Bs + (nbase + nt * 16 + mrow) * 72 + ks * 32 + quad * 8);
                    acc[nt] = __builtin_amdgcn_mfma_f32_16x16x32_bf16(a, b, acc[nt], 0, 0, 0);
                }
            }
        }
    }
    // epilogue: bias+relu into As (as [32 m][256 n] stride 264), then coalesced store
    __syncthreads();
    #pragma unroll
    for (int nt = 0; nt < 8; ++nt) {
        int col = nbase + nt * 16 + mrow;
        float bv = b2f(bias[col]);
        #pragma unroll
        for (int v = 0; v < 4; ++v) {
            float val = acc[nt][v] + bv;
            val = val > 0.0f ? val : 0.0f;
            As[((wave & 1) * 16 + quad * 4 + v) * 264 + col] = f2b(val);
        }
    }
    __syncthreads();
    int row = threadIdx.x >> 3;
    int c0 = (threadIdx.x & 7) * 32;
    u16* dst = xc + (size_t)(m0 + row) * 768 + colbase + c0;
    const u16* srcp = As + row * 264 + c0;
    #pragma unroll
    for (int c = 0; c < 4; ++c)
        *(bf8*)(dst + c * 8) = *(const bf8*)(srcp + c * 8);
}

// ---------------- pool scorer: one wave per node, all 9 dots fused ----------------
__launch_bounds__(256)
__global__ void k_pool(const u16* __restrict__ xc, const u16* __restrict__ parms,
                       float* __restrict__ p, float* __restrict__ score) {
    int n = blockIdx.x * 4 + (threadIdx.x >> 6);
    if (n >= N_NODES) return;
    int lane = threadIdx.x & 63;
    const u16* xr = xc + (size_t)n * 768;
    float acc[9];
    #pragma unroll
    for (int rr = 0; rr < 9; ++rr) acc[rr] = 0.0f;
    #pragma unroll
    for (int q = 0; q < 12; ++q) {
        int f = lane + 64 * q;
        float xv = b2f(xr[f]);
        #pragma unroll
        for (int rr = 0; rr < 8; ++rr)
            acc[rr] += xv * b2f(parms[P_POOL_W + rr * 768 + f]);
        acc[8] += xv * b2f(parms[P_POOL_ROOT + f]);
    }
    #pragma unroll
    for (int rr = 0; rr < 9; ++rr) acc[rr] = wred(acc[rr]);
    if (lane == 0) {
        #pragma unroll
        for (int rr = 0; rr < 8; ++rr) p[rr * N_NODES + n] = acc[rr];
        score[n] = acc[8] + b2f(parms[P_POOL_BIAS]);
    }
}
__global__ void k_scatter_pool(const int* __restrict__ src, const int* __restrict__ dst,
                               const int* __restrict__ et, const float* __restrict__ inv,
                               const float* __restrict__ p, float* __restrict__ score) {
    int e = blockIdx.x * 256 + threadIdx.x;
    if (e >= N_EDGES) return;
    int r = et[e] & 7;
    unsigned s = (unsigned)src[e]; if (s >= N_NODES) s = 0;
    unsigned d = (unsigned)dst[e]; if (d >= N_NODES) d = 0;
    atomicAdd(&score[d], inv[d * 8 + r] * p[r * N_NODES + s]);
}

// ---------------- per-graph top-K sort ----------------
__launch_bounds__(256)
__global__ void k_sort(const float* __restrict__ score, unsigned int* __restrict__ topidx,
                       float* __restrict__ topv) {
    __shared__ unsigned long long keys[512];
    __shared__ float vals[512];
    int g = blockIdx.x, tid = threadIdx.x;
    for (int i = tid; i < 512; i += 256) {
        unsigned long long key;
        float v = 0.0f;
        if (i < NPG) {
            v = tanhf(score[g * NPG + i]);
            unsigned int u = __float_as_uint(v);
            u = (u & 0x80000000u) ? ~u : (u | 0x80000000u);
            u = ~u;
            key = ((unsigned long long)u << 32) | (unsigned int)i;
        } else {
            key = 0xFFFFFFFFFFFFFFFFull;
        }
        keys[i] = key;
        vals[i] = v;
    }
    __syncthreads();
    for (int k = 2; k <= 512; k <<= 1)
        for (int j = k >> 1; j > 0; j >>= 1) {
            for (int i = tid; i < 512; i += 256) {
                int ixj = i ^ j;
                if (ixj > i) {
                    bool up = ((i & k) == 0);
                    unsigned long long a = keys[i], b = keys[ixj];
                    if ((a > b) == up) { keys[i] = b; keys[ixj] = a; }
                }
            }
            __syncthreads();
        }
    if (tid < KTOP) {
        int idx = (int)(keys[tid] & 511u);
        topidx[g * 256 + tid] = (unsigned)idx;
        topv[g * 256 + tid] = vals[idx];
    }
}

// ---------------- parallel weighted readout ----------------
__launch_bounds__(256)
__global__ void k_readout(const unsigned int* __restrict__ topidx,
                          const float* __restrict__ topv,
                          const u16* __restrict__ xc, float* __restrict__ readout) {
    __shared__ unsigned int sidx[KTOP];
    __shared__ float sv[KTOP];
    __shared__ float part[256];
    int g = blockIdx.x, cb = blockIdx.y;
    int tid = threadIdx.x;
    if (tid < KTOP) { sidx[tid] = topidx[g * 256 + tid]; sv[tid] = topv[g * 256 + tid]; }
    __syncthreads();
    int fl = tid & 63, ng = tid >> 6;
    int f = cb * 64 + fl;
    float acc = 0.0f;
    for (int j = ng; j < KTOP; j += 4)
        acc += sv[j] * b2f(xc[(size_t)(g * NPG + sidx[j]) * 768 + f]);
    part[tid] = acc;
    __syncthreads();
    if (tid < 64) {
        float s = part[tid] + part[64 + tid] + part[128 + tid] + part[192 + tid];
        readout[(size_t)g * 768 + cb * 64 + tid] = s * (1.0f / (float)KTOP);
    }
}

// ---------------- fc1 + LSTM input precompute ----------------
__global__ void k_fc1(const float* __restrict__ readout, const u16* __restrict__ parms,
                      float* __restrict__ h1) {
    int wid = blockIdx.x * 4 + (threadIdx.x >> 6);
    if (wid >= NGRAPH * 256) return;
    int g = wid >> 8, o = wid & 255, lane = threadIdx.x & 63;
    const float* rr = readout + (size_t)g * 768;
    const u16* w = parms + P_FC1_W + (size_t)o * 768;
    float s = 0.0f;
    #pragma unroll
    for (int q = 0; q < 12; ++q) { int f = lane + 64 * q; s += rr[f] * b2f(w[f]); }
    s = wred(s);
    if (lane == 0) { s += b2f(parms[P_FC1_B + o]); h1[g * 256 + o] = s > 0.0f ? s : 0.0f; }
}
__global__ void k_gx(const float* __restrict__ h1, const u16* __restrict__ parms,
                     float* __restrict__ gx) {
    int wid = blockIdx.x * 4 + (threadIdx.x >> 6);
    if (wid >= NGRAPH * 1024) return;
    int t = wid >> 10, j = wid & 1023, lane = threadIdx.x & 63;
    const float* xr = h1 + t * 256;
    const u16* w = parms + P_W_IH + (size_t)j * 256;
    float s = 0.0f;
    #pragma unroll
    for (int q = 0; q < 4; ++q) { int f = lane + 64 * q; s += xr[f] * b2f(w[f]); }
    s = wred(s);
    if (lane == 0) gx[t * 1024 + j] = s + b2f(parms[P_B_IH + j]) + b2f(parms[P_B_HH + j]);
}

// ---------------- sequential LSTM: half of W_hh pinned in VGPRs, half streamed -----------
__launch_bounds__(1024, 4)
__global__ void k_lstm(const float* __restrict__ gx, const unsigned int* __restrict__ whh4,
                       const u16* __restrict__ parms, void* __restrict__ out,
                       const unsigned int* __restrict__ flag) {
    __shared__ float hs[256];
    __shared__ unsigned int hs2[128];
    __shared__ float gs[1024];
    __shared__ float red[2];
    int tid = threadIdx.x;
    u4v wr[16];
    #pragma unroll
    for (int q = 0; q < 16; ++q)
        wr[q] = *(const u4v*)(whh4 + (((size_t)q * 1024) + tid) * 4);
    // pin the 64 weight registers so the compiler cannot re-load them each step
    asm volatile("" : "+v"(wr[0]), "+v"(wr[1]), "+v"(wr[2]), "+v"(wr[3]),
                      "+v"(wr[4]), "+v"(wr[5]), "+v"(wr[6]), "+v"(wr[7]),
                      "+v"(wr[8]), "+v"(wr[9]), "+v"(wr[10]), "+v"(wr[11]),
                      "+v"(wr[12]), "+v"(wr[13]), "+v"(wr[14]), "+v"(wr[15]));
    if (tid < 256) hs[tid] = 0.0f;
    if (tid < 128) hs2[tid] = 0u;
    float c = 0.0f;
    __syncthreads();
    for (int t = 0; t < NGRAPH; ++t) {
        float g = gx[t * 1024 + tid];
        #pragma unroll
        for (int q = 0; q < 16; ++q) {
            g = fdot2u(wr[q][0], hs2[q * 4 + 0], g);
            g = fdot2u(wr[q][1], hs2[q * 4 + 1], g);
            g = fdot2u(wr[q][2], hs2[q * 4 + 2], g);
            g = fdot2u(wr[q][3], hs2[q * 4 + 3], g);
        }
        #pragma unroll 4
        for (int q = 16; q < 32; ++q) {
            u4v wv = *(const u4v*)(whh4 + (((size_t)q * 1024) + tid) * 4);
            g = fdot2u(wv[0], hs2[q * 4 + 0], g);
            g = fdot2u(wv[1], hs2[q * 4 + 1], g);
            g = fdot2u(wv[2], hs2[q * 4 + 2], g);
            g = fdot2u(wv[3], hs2[q * 4 + 3], g);
        }
        gs[tid] = g;
        __syncthreads();
        if (tid < 256) {
            float gi = 1.0f / (1.0f + expf(-gs[tid]));
            float gf = 1.0f / (1.0f + expf(-gs[256 + tid]));
            float gg = tanhf(gs[512 + tid]);
            float go = 1.0f / (1.0f + expf(-gs[768 + tid]));
            c = gf * c + gi * gg;
            float h = go * tanhf(c);
            hs[tid] = h;
            float ho = __shfl(h, (tid & 63) ^ 1);
            if (!(tid & 1)) hs2[tid >> 1] = packh2(h, ho);
        }
        __syncthreads();
    }
    if (tid < 128) {
        int cls = tid >> 6, lane = tid & 63;
        float s = 0.0f;
        #pragma unroll
        for (int q = 0; q < 4; ++q) {
            int d = lane + 64 * q;
            s += hs[d] * b2f(parms[P_FC2_W + cls * 256 + d]);
        }
        s = wred(s);
        if (lane == 0) red[cls] = s + b2f(parms[P_FC2_B + cls]);
    }
    __syncthreads();
    if (tid == 0) {
        float l0 = red[0], l1 = red[1];
        float m = fmaxf(l0, l1);
        float lse = m + logf(expf(l0 - m) + expf(l1 - m));
        float o0 = l0 - lse, o1 = l1 - lse;
        if (*flag) { ((float*)out)[0] = o0; ((float*)out)[1] = o1; }
        else       { ((u16*)out)[0] = f2b(o0); ((u16*)out)[1] = f2b(o1); }
    }
}

// ---------------- workspace plan (single path, ~41 MB) ----------------
struct WS {
    unsigned int* flag; unsigned int* cnt; float* inv; unsigned int* seg; unsigned int* ctr;
    unsigned int* skey; float* sw; unsigned int* bsum;
    u16* Wt2; u16* xc; float* p; float* score;
    unsigned int* topidx; float* topv;
    float* readout; float* h1; float* gx; unsigned int* whh4; u16* parms;
    size_t need;
};
static WS plan(char* base) {
    WS w; size_t off = 0;
    auto take = [&](size_t bytes) -> char* {
        char* p = base + off; off += (bytes + 255) & ~(size_t)255; return p;
    };
    w.flag    = (unsigned int*)take(256);
    w.cnt     = (unsigned int*)take((size_t)NSEG * 4);
    w.inv     = (float*)take((size_t)NSEG * 4);
    w.seg     = (unsigned int*)take((size_t)(NSEG + 1) * 4);
    w.ctr     = (unsigned int*)take((size_t)NSEG * 4);
    w.skey    = (unsigned int*)take((size_t)N_EDGES * 4);
    w.sw      = (float*)take((size_t)N_EDGES * 4);
    w.bsum    = (unsigned int*)take(1024 * 4);
    w.Wt2     = (u16*)take((size_t)3 * 36 * 256 * 64 * 2);
    w.xc      = (u16*)take((size_t)N_NODES * 768 * 2);
    w.p       = (float*)take((size_t)8 * N_NODES * 4);
    w.score   = (float*)take((size_t)N_NODES * 4);
    w.topidx  = (unsigned int*)take((size_t)NGRAPH * 256 * 4);
    w.topv    = (float*)take((size_t)NGRAPH * 256 * 4);
    w.readout = (float*)take((size_t)NGRAPH * 768 * 4);
    w.h1      = (float*)take((size_t)NGRAPH * 256 * 4);
    w.gx      = (float*)take((size_t)NGRAPH * 1024 * 4);
    w.whh4    = (unsigned int*)take((size_t)32 * 1024 * 4 * 4);
    w.parms   = (u16*)take((size_t)P_TOTAL * 2);
    w.need = off;
    return w;
}

extern "C" void kernel_launch(void* const* d_in, const int* in_sizes, int n_in,
                              void* d_out, int out_size, void* d_ws, size_t ws_size,
                              hipStream_t stream) {
    (void)in_sizes; (void)n_in; (void)out_size; (void)ws_size;
    const void* x        = d_in[0];
    const int* edge_index= (const int*)d_in[1];
    const int* edge_attr = (const int*)d_in[2];
    const void* conv_W   = d_in[4];
    const void* conv_root= d_in[5];
    const void* conv_bias= d_in[6];
    const void* pool_W   = d_in[7];
    const void* pool_root= d_in[8];
    const void* pool_bias= d_in[9];
    const void* fc1_W    = d_in[10];
    const void* fc1_b    = d_in[11];
    const void* W_ih     = d_in[12];
    const void* W_hh     = d_in[13];
    const void* b_ih     = d_in[14];
    const void* b_hh     = d_in[15];
    const void* fc2_W    = d_in[16];
    const void* fc2_b    = d_in[17];

    const int* e_src = edge_index;
    const int* e_dst = edge_index + N_EDGES;

    WS w = plan((char*)d_ws);

    k_init<<<(NSEG + 255) / 256, 256, 0, stream>>>(w.flag, w.cnt, w.ctr);
    k_detect1<<<64, 256, 0, stream>>>((const u16*)x, 1 << 18, w.flag);
    k_detect2<<<1, 1, 0, stream>>>(w.flag);

    k_count<<<1250, 256, 0, stream>>>(e_dst, edge_attr, w.cnt);
    k_inv<<<(NSEG + 255) / 256, 256, 0, stream>>>(w.cnt, w.inv, NSEG);
    k_scan1<<<625, 256, 0, stream>>>(w.cnt, w.seg, w.bsum);
    k_scan2<<<1, 1024, 0, stream>>>(w.bsum, 625);
    k_scan3<<<(NSEG + 255) / 256, 256, 0, stream>>>(w.seg, w.bsum);
    k_place<<<1250, 256, 0, stream>>>(e_src, e_dst, edge_attr, w.seg, w.ctr, w.inv,
                                      w.skey, w.sw);

    k_cvt_all<<<(P_TOTAL + 255) / 256, 256, 0, stream>>>(
        conv_bias, pool_W, pool_root, pool_bias, fc1_W, fc1_b,
        W_ih, b_ih, b_hh, fc2_W, fc2_b, w.parms, w.flag);

    k_stage_x<<<20000, 256, 0, stream>>>(x, w.xc, w.flag);
    k_transpose2<<<6912, 256, 0, stream>>>(conv_W, conv_root, w.Wt2, w.flag);
    k_whh4<<<512, 256, 0, stream>>>(W_hh, w.whh4, w.flag);

    for (int l = 0; l < 3; ++l) {
        const u16* xprev = w.xc + (l == 0 ? 512 : (l - 1) * 256);
        const u16* WtL = w.Wt2 + (size_t)l * 36 * 16384;
        const u16* bias = w.parms + P_CONV_BIAS + l * 256;
        k_layer<<<625, 256, 0, stream>>>(w.seg, w.skey, w.sw, xprev, WtL, bias,
                                         w.xc, l * 256);
    }

    k_pool<<<5000, 256, 0, stream>>>(w.xc, w.parms, w.p, w.score);
    k_scatter_pool<<<1250, 256, 0, stream>>>(e_src, e_dst, edge_attr, w.inv, w.p, w.score);
    k_sort<<<NGRAPH, 256, 0, stream>>>(w.score, w.topidx, w.topv);
    k_readout<<<dim3(NGRAPH, 12), 256, 0, stream>>>(w.topidx, w.topv, w.xc, w.readout);
    k_fc1<<<2560, 256, 0, stream>>>(w.readout, w.parms, w.h1);
    k_gx<<<10240, 256, 0, stream>>>(w.h1, w.parms, w.gx);
    k_lstm<<<1, 1024, 0, stream>>>(w.gx, w.whh4, w.parms, d_out, w.flag);
}

// Round 9
// 793.498 us; speedup vs baseline: 1.2744x; 1.2744x over previous
//
#include <hip/hip_runtime.h>

typedef unsigned short u16;
typedef short bf8 __attribute__((ext_vector_type(8)));
typedef float f4 __attribute__((ext_vector_type(4)));
typedef _Float16 h2v __attribute__((ext_vector_type(2)));
typedef __fp16 g2v __attribute__((ext_vector_type(2)));
typedef unsigned int u4v __attribute__((ext_vector_type(4)));

#define N_NODES 20000
#define N_EDGES 320000
#define NGRAPH 40
#define NPG 500
#define KTOP 250
#define NSEG (N_NODES * 8)

// parms arena offsets (u16 elements)
#define P_CONV_BIAS 0
#define P_POOL_W    768
#define P_POOL_ROOT 6912
#define P_POOL_BIAS 7680
#define P_FC1_W     7688
#define P_FC1_B     204296
#define P_W_IH      204552
#define P_B_IH      466696
#define P_B_HH      467720
#define P_FC2_W     468744
#define P_FC2_B     469256
#define P_TOTAL     469264

__device__ __forceinline__ float b2f(u16 u) {
    union { unsigned int i; float f; } v; v.i = ((unsigned int)u) << 16; return v.f;
}
__device__ __forceinline__ u16 f2b(float f) {
    union { float f; unsigned int i; } v; v.f = f;
    unsigned int x = v.i;
    return (u16)((x + 0x7fffu + ((x >> 16) & 1u)) >> 16);
}
__device__ __forceinline__ float wred(float s) {
    #pragma unroll
    for (int off = 32; off > 0; off >>= 1) s += __shfl_down(s, off);
    return s;
}
__device__ __forceinline__ float fdot2u(unsigned a, unsigned b, float c) {
#if __has_builtin(__builtin_amdgcn_fdot2)
    union { unsigned u; h2v h; } ua, ub; ua.u = a; ub.u = b;
    return __builtin_amdgcn_fdot2(ua.h, ub.h, c, false);
#else
    union { unsigned u; g2v h; } ua, ub; ua.u = a; ub.u = b;
    return c + (float)ua.h[0] * (float)ub.h[0] + (float)ua.h[1] * (float)ub.h[1];
#endif
}
__device__ __forceinline__ unsigned packh2(float a, float b) {
    g2v h = __builtin_amdgcn_cvt_pkrtz(a, b);
    union { g2v h; unsigned u; } v; v.h = h; return v.u;
}

// ---------------- init: zero flag + cnt + ctr ----------------
__global__ void k_init(unsigned int* __restrict__ flag, unsigned int* __restrict__ cnt,
                       unsigned int* __restrict__ ctr) {
    int i = blockIdx.x * 256 + threadIdx.x;
    if (i < 64) flag[i] = 0u;
    if (i < NSEG) { cnt[i] = 0u; ctr[i] = 0u; }
}

// ---------------- dtype detection (parallel) ----------------
__global__ void k_detect1(const u16* __restrict__ xr, int n, unsigned int* __restrict__ fb) {
    unsigned int local = 0;
    for (int i = blockIdx.x * 256 + threadIdx.x; i < n; i += 64 * 256) {
        unsigned int u = xr[i];
        if (((u >> 7) & 0xFFu) == 0xFFu) local++;
    }
    local = (unsigned int)wred((float)local);
    if ((threadIdx.x & 63) == 0 && local) atomicAdd(&fb[1], local);
}
__global__ void k_detect2(unsigned int* __restrict__ fb) {
    fb[0] = (fb[1] > 8u) ? 1u : 0u;
}

__device__ __forceinline__ u16 load_cvt(const void* src, size_t i, bool f32) {
    return f32 ? f2b(((const float*)src)[i]) : ((const u16*)src)[i];
}

// ---------------- one-shot param canonicalization ----------------
__global__ void k_cvt_all(const void* conv_bias, const void* pool_W, const void* pool_root,
                          const void* pool_bias, const void* fc1_W, const void* fc1_b,
                          const void* W_ih, const void* b_ih, const void* b_hh,
                          const void* fc2_W, const void* fc2_b,
                          u16* __restrict__ parms, const unsigned int* __restrict__ flag) {
    int i = blockIdx.x * 256 + threadIdx.x;
    if (i >= P_TOTAL) return;
    bool f32 = (*flag != 0u);
    u16 v;
    if      (i < P_CONV_BIAS + 768)    v = load_cvt(conv_bias, i - P_CONV_BIAS, f32);
    else if (i < P_POOL_W + 6144)      v = load_cvt(pool_W,    i - P_POOL_W, f32);
    else if (i < P_POOL_ROOT + 768)    v = load_cvt(pool_root, i - P_POOL_ROOT, f32);
    else if (i < P_POOL_BIAS + 1)      v = load_cvt(pool_bias, i - P_POOL_BIAS, f32);
    else if (i < P_FC1_W && i >= P_POOL_BIAS) return;        // alignment gap
    else if (i < P_FC1_W + 196608)     v = load_cvt(fc1_W,    i - P_FC1_W, f32);
    else if (i < P_FC1_B + 256)        v = load_cvt(fc1_b,    i - P_FC1_B, f32);
    else if (i < P_W_IH + 262144)      v = load_cvt(W_ih,     i - P_W_IH, f32);
    else if (i < P_B_IH + 1024)        v = load_cvt(b_ih,     i - P_B_IH, f32);
    else if (i < P_B_HH + 1024)        v = load_cvt(b_hh,     i - P_B_HH, f32);
    else if (i < P_FC2_W + 512)        v = load_cvt(fc2_W,    i - P_FC2_W, f32);
    else if (i < P_FC2_B + 2)          v = load_cvt(fc2_b,    i - P_FC2_B, f32);
    else return;
    parms[i] = v;
}

// stage x (canonical bf16) into xc[:, 512:768]
__global__ void k_stage_x(const void* __restrict__ src, u16* __restrict__ xc,
                          const unsigned int* __restrict__ flag) {
    int i = blockIdx.x * 256 + threadIdx.x;
    if (i >= N_NODES * 256) return;
    u16 v = load_cvt(src, i, *flag != 0u);
    int n = i >> 8, f = i & 255;
    xc[(size_t)n * 768 + 512 + f] = v;
}

// ---------------- degree counts ----------------
__global__ void k_count(const int* __restrict__ dst, const int* __restrict__ et,
                        unsigned int* __restrict__ cnt) {
    int e = blockIdx.x * 256 + threadIdx.x;
    if (e < N_EDGES) {
        unsigned d = (unsigned)dst[e]; if (d >= N_NODES) d = 0;
        unsigned r = (unsigned)et[e] & 7u;
        atomicAdd(&cnt[d * 8 + r], 1u);
    }
}
__global__ void k_inv(const unsigned int* __restrict__ cnt, float* __restrict__ inv, int n) {
    int i = blockIdx.x * 256 + threadIdx.x;
    if (i < n) {
        unsigned int c = cnt[i];
        inv[i] = 1.0f / (float)(c < 1u ? 1u : c);
    }
}

// ---------------- prefix scan (exclusive) over cnt[160000] ----------------
__global__ void k_scan1(const unsigned int* __restrict__ cnt, unsigned int* __restrict__ seg,
                        unsigned int* __restrict__ bsum) {
    __shared__ unsigned int s[256];
    int t = threadIdx.x, i = blockIdx.x * 256 + t;
    unsigned int v = (i < NSEG) ? cnt[i] : 0u;
    s[t] = v;
    __syncthreads();
    for (int off = 1; off < 256; off <<= 1) {
        unsigned int add = (t >= off) ? s[t - off] : 0u;
        __syncthreads();
        s[t] += add;
        __syncthreads();
    }
    if (i < NSEG) seg[i] = s[t] - v;
    if (t == 255) bsum[blockIdx.x] = s[255];
}
__global__ void k_scan2(unsigned int* __restrict__ bsum, int nb) {
    __shared__ unsigned int s[1024];
    int t = threadIdx.x;
    unsigned int v = (t < nb) ? bsum[t] : 0u;
    s[t] = v;
    __syncthreads();
    for (int off = 1; off < 1024; off <<= 1) {
        unsigned int add = (t >= off) ? s[t - off] : 0u;
        __syncthreads();
        s[t] += add;
        __syncthreads();
    }
    if (t < nb) bsum[t] = s[t] - v;
}
__global__ void k_scan3(unsigned int* __restrict__ seg, const unsigned int* __restrict__ bsum) {
    int i = blockIdx.x * 256 + threadIdx.x;
    if (i < NSEG) seg[i] += bsum[i >> 8];
    if (i == 0) seg[NSEG] = N_EDGES;
}
// place edges into (dst,rel)-sorted order; skey = src node id
__global__ void k_place(const int* __restrict__ src, const int* __restrict__ dst,
                        const int* __restrict__ et, const unsigned int* __restrict__ seg,
                        unsigned int* __restrict__ ctr, const float* __restrict__ inv,
                        unsigned int* __restrict__ skey, float* __restrict__ sw) {
    int e = blockIdx.x * 256 + threadIdx.x;
    if (e >= N_EDGES) return;
    unsigned s = (unsigned)src[e]; if (s >= N_NODES) s = 0;
    unsigned d = (unsigned)dst[e]; if (d >= N_NODES) d = 0;
    unsigned r = (unsigned)et[e] & 7u;
    unsigned key = d * 8 + r;
    unsigned pos = seg[key] + atomicAdd(&ctr[key], 1u);
    skey[pos] = s;
    sw[pos] = inv[key];
}

// ---------------- weight prep: chunked Wt [l][ck=36][n=256][kk=64] ----------------
__global__ void k_transpose2(const void* __restrict__ conv_W, const void* __restrict__ conv_root,
                             u16* __restrict__ Wt, const unsigned int* __restrict__ flag) {
    int idx = blockIdx.x * 256 + threadIdx.x;
    if (idx >= 3 * 36 * 256 * 64) return;
    bool f32 = (*flag != 0u);
    int kk = idx & 63;
    int n = (idx >> 6) & 255;
    int lc = idx >> 14;            // l*36 + ck
    int l = lc / 36, ck = lc % 36;
    int k = ck * 64 + kk;
    u16 v;
    if (k < 2048) {
        int r = k >> 8, i = k & 255;
        v = load_cvt(conv_W, ((size_t)((l * 8 + r) * 256 + i)) * 256 + n, f32);
    } else {
        int i = k - 2048;
        v = load_cvt(conv_root, ((size_t)(l * 256 + i)) * 256 + n, f32);
    }
    Wt[idx] = v;
}
// W_hh [j][i] -> whh4[i4][j][4] packed f16 pairs (i2 = i4*4+c, pair = (2*i2, 2*i2+1))
__global__ void k_whh4(const void* __restrict__ W_hh, unsigned int* __restrict__ whh4,
                       const unsigned int* __restrict__ flag) {
    int idx = blockIdx.x * 256 + threadIdx.x;     // 32*1024*4
    if (idx >= 32 * 1024 * 4) return;
    int c = idx & 3, j = (idx >> 2) & 1023, i4 = idx >> 12;
    int i2 = i4 * 4 + c;
    bool f32 = (*flag != 0u);
    float a, b;
    if (f32) {
        a = ((const float*)W_hh)[j * 256 + 2 * i2];
        b = ((const float*)W_hh)[j * 256 + 2 * i2 + 1];
    } else {
        a = b2f(((const u16*)W_hh)[j * 256 + 2 * i2]);
        b = b2f(((const u16*)W_hh)[j * 256 + 2 * i2 + 1]);
    }
    whh4[idx] = packh2(a, b);
}

// ---------------- fused RGCN layer v2 ----------------
// grid 625 blocks (32 dst rows), 256 threads. Gather: thread = (row = t&31,
// 32-col group = t>>5), 4 independent b128 loads/edge. No B LDS stage: MFMA B
// fragments load straight from L2-resident Wt (wave w owns 64-col N strip).
// acc[nt][mh]: nt = 4 col-subtiles of 16, mh = 2 row-halves of 16.
__launch_bounds__(256, 4)
__global__ void k_layer(const unsigned int* __restrict__ seg,
                        const unsigned int* __restrict__ skey,
                        const float* __restrict__ sw,
                        const u16* __restrict__ xprev,      // stride 768
                        const u16* __restrict__ WtL,        // [36][256][64]
                        const u16* __restrict__ bias,
                        u16* __restrict__ xc, int colbase) {
    __shared__ u16 As[32 * 264];
    int wave = threadIdx.x >> 6, lane = threadIdx.x & 63;
    int m0 = blockIdx.x * 32;
    int mrow = lane & 15, quad = lane >> 4;
    int nbase = wave * 64;
    int grow = threadIdx.x & 31;
    int ggrp = threadIdx.x >> 5;
    int gm = m0 + grow;
    const u16* gcol = xprev + ggrp * 32;

    f4 acc[4][2];
    #pragma unroll
    for (int nt = 0; nt < 4; ++nt)
        #pragma unroll
        for (int mh = 0; mh < 2; ++mh) acc[nt][mh] = (f4){0.0f, 0.0f, 0.0f, 0.0f};

    for (int rg = 0; rg < 9; ++rg) {
        __syncthreads();                 // previous MFMA reads of As done
        if (rg < 8) {
            float a[32];
            #pragma unroll
            for (int c = 0; c < 32; ++c) a[c] = 0.0f;
            unsigned nb = seg[gm * 8 + rg], ne = seg[gm * 8 + rg + 1];
            for (unsigned i = nb; i < ne; ++i) {
                float wgt = sw[i];
                const u16* row = gcol + (size_t)skey[i] * 768;
                #pragma unroll
                for (int k8 = 0; k8 < 4; ++k8) {
                    bf8 u = *(const bf8*)(row + k8 * 8);
                    #pragma unroll
                    for (int c = 0; c < 8; ++c)
                        a[k8 * 8 + c] += wgt * b2f((u16)u[c]);
                }
            }
            #pragma unroll
            for (int k8 = 0; k8 < 4; ++k8) {
                bf8 o;
                #pragma unroll
                for (int c = 0; c < 8; ++c) o[c] = (short)f2b(a[k8 * 8 + c]);
                *(bf8*)(As + grow * 264 + ggrp * 32 + k8 * 8) = o;
            }
        } else {
            const u16* row = gcol + (size_t)gm * 768;
            #pragma unroll
            for (int k8 = 0; k8 < 4; ++k8)
                *(bf8*)(As + grow * 264 + ggrp * 32 + k8 * 8) =
                    *(const bf8*)(row + k8 * 8);
        }
        __syncthreads();                 // gather visible
        #pragma unroll
        for (int c4 = 0; c4 < 4; ++c4) {
            const u16* Bck = WtL + (size_t)(rg * 4 + c4) * 16384;
            #pragma unroll
            for (int ks = 0; ks < 2; ++ks) {
                bf8 a0 = *(const bf8*)(As + mrow * 264 + c4 * 64 + ks * 32 + quad * 8);
                bf8 a1 = *(const bf8*)(As + (16 + mrow) * 264 + c4 * 64 + ks * 32 + quad * 8);
                #pragma unroll
                for (int nt = 0; nt < 4; ++nt) {
                    bf8 b = *(const bf8*)(Bck + (size_t)(nbase + nt * 16 + mrow) * 64
                                          + ks * 32 + quad * 8);
                    acc[nt][0] = __builtin_amdgcn_mfma_f32_16x16x32_bf16(a0, b, acc[nt][0], 0, 0, 0);
                    acc[nt][1] = __builtin_amdgcn_mfma_f32_16x16x32_bf16(a1, b, acc[nt][1], 0, 0, 0);
                }
            }
        }
    }
    // epilogue: bias+relu into As ([32 m][256 n] stride 264), coalesced store
    __syncthreads();
    #pragma unroll
    for (int nt = 0; nt < 4; ++nt) {
        int col = nbase + nt * 16 + mrow;
        float bv = b2f(bias[col]);
        #pragma unroll
        for (int mh = 0; mh < 2; ++mh)
            #pragma unroll
            for (int v = 0; v < 4; ++v) {
                float val = acc[nt][mh][v] + bv;
                val = val > 0.0f ? val : 0.0f;
                As[(mh * 16 + quad * 4 + v) * 264 + col] = f2b(val);
            }
    }
    __syncthreads();
    int row = threadIdx.x >> 3;
    int c0 = (threadIdx.x & 7) * 32;
    u16* dst = xc + (size_t)(m0 + row) * 768 + colbase + c0;
    const u16* srcp = As + row * 264 + c0;
    #pragma unroll
    for (int c = 0; c < 4; ++c)
        *(bf8*)(dst + c * 8) = *(const bf8*)(srcp + c * 8);
}

// ---------------- pool scorer: one wave per node, all 9 dots fused ----------------
__launch_bounds__(256)
__global__ void k_pool(const u16* __restrict__ xc, const u16* __restrict__ parms,
                       float* __restrict__ p, float* __restrict__ score) {
    int n = blockIdx.x * 4 + (threadIdx.x >> 6);
    if (n >= N_NODES) return;
    int lane = threadIdx.x & 63;
    const u16* xr = xc + (size_t)n * 768;
    float acc[9];
    #pragma unroll
    for (int rr = 0; rr < 9; ++rr) acc[rr] = 0.0f;
    #pragma unroll
    for (int q = 0; q < 12; ++q) {
        int f = lane + 64 * q;
        float xv = b2f(xr[f]);
        #pragma unroll
        for (int rr = 0; rr < 8; ++rr)
            acc[rr] += xv * b2f(parms[P_POOL_W + rr * 768 + f]);
        acc[8] += xv * b2f(parms[P_POOL_ROOT + f]);
    }
    #pragma unroll
    for (int rr = 0; rr < 9; ++rr) acc[rr] = wred(acc[rr]);
    if (lane == 0) {
        #pragma unroll
        for (int rr = 0; rr < 8; ++rr) p[rr * N_NODES + n] = acc[rr];
        score[n] = acc[8] + b2f(parms[P_POOL_BIAS]);
    }
}
__global__ void k_scatter_pool(const int* __restrict__ src, const int* __restrict__ dst,
                               const int* __restrict__ et, const float* __restrict__ inv,
                               const float* __restrict__ p, float* __restrict__ score) {
    int e = blockIdx.x * 256 + threadIdx.x;
    if (e >= N_EDGES) return;
    int r = et[e] & 7;
    unsigned s = (unsigned)src[e]; if (s >= N_NODES) s = 0;
    unsigned d = (unsigned)dst[e]; if (d >= N_NODES) d = 0;
    atomicAdd(&score[d], inv[d * 8 + r] * p[r * N_NODES + s]);
}

// ---------------- per-graph top-K sort ----------------
__launch_bounds__(256)
__global__ void k_sort(const float* __restrict__ score, unsigned int* __restrict__ topidx,
                       float* __restrict__ topv) {
    __shared__ unsigned long long keys[512];
    __shared__ float vals[512];
    int g = blockIdx.x, tid = threadIdx.x;
    for (int i = tid; i < 512; i += 256) {
        unsigned long long key;
        float v = 0.0f;
        if (i < NPG) {
            v = tanhf(score[g * NPG + i]);
            unsigned int u = __float_as_uint(v);
            u = (u & 0x80000000u) ? ~u : (u | 0x80000000u);
            u = ~u;
            key = ((unsigned long long)u << 32) | (unsigned int)i;
        } else {
            key = 0xFFFFFFFFFFFFFFFFull;
        }
        keys[i] = key;
        vals[i] = v;
    }
    __syncthreads();
    for (int k = 2; k <= 512; k <<= 1)
        for (int j = k >> 1; j > 0; j >>= 1) {
            for (int i = tid; i < 512; i += 256) {
                int ixj = i ^ j;
                if (ixj > i) {
                    bool up = ((i & k) == 0);
                    unsigned long long a = keys[i], b = keys[ixj];
                    if ((a > b) == up) { keys[i] = b; keys[ixj] = a; }
                }
            }
            __syncthreads();
        }
    if (tid < KTOP) {
        int idx = (int)(keys[tid] & 511u);
        topidx[g * 256 + tid] = (unsigned)idx;
        topv[g * 256 + tid] = vals[idx];
    }
}

// ---------------- parallel weighted readout ----------------
__launch_bounds__(256)
__global__ void k_readout(const unsigned int* __restrict__ topidx,
                          const float* __restrict__ topv,
                          const u16* __restrict__ xc, float* __restrict__ readout) {
    __shared__ unsigned int sidx[KTOP];
    __shared__ float sv[KTOP];
    __shared__ float part[256];
    int g = blockIdx.x, cb = blockIdx.y;
    int tid = threadIdx.x;
    if (tid < KTOP) { sidx[tid] = topidx[g * 256 + tid]; sv[tid] = topv[g * 256 + tid]; }
    __syncthreads();
    int fl = tid & 63, ng = tid >> 6;
    int f = cb * 64 + fl;
    float acc = 0.0f;
    for (int j = ng; j < KTOP; j += 4)
        acc += sv[j] * b2f(xc[(size_t)(g * NPG + sidx[j]) * 768 + f]);
    part[tid] = acc;
    __syncthreads();
    if (tid < 64) {
        float s = part[tid] + part[64 + tid] + part[128 + tid] + part[192 + tid];
        readout[(size_t)g * 768 + cb * 64 + tid] = s * (1.0f / (float)KTOP);
    }
}

// ---------------- fc1 + LSTM input precompute ----------------
__global__ void k_fc1(const float* __restrict__ readout, const u16* __restrict__ parms,
                      float* __restrict__ h1) {
    int wid = blockIdx.x * 4 + (threadIdx.x >> 6);
    if (wid >= NGRAPH * 256) return;
    int g = wid >> 8, o = wid & 255, lane = threadIdx.x & 63;
    const float* rr = readout + (size_t)g * 768;
    const u16* w = parms + P_FC1_W + (size_t)o * 768;
    float s = 0.0f;
    #pragma unroll
    for (int q = 0; q < 12; ++q) { int f = lane + 64 * q; s += rr[f] * b2f(w[f]); }
    s = wred(s);
    if (lane == 0) { s += b2f(parms[P_FC1_B + o]); h1[g * 256 + o] = s > 0.0f ? s : 0.0f; }
}
__global__ void k_gx(const float* __restrict__ h1, const u16* __restrict__ parms,
                     float* __restrict__ gx) {
    int wid = blockIdx.x * 4 + (threadIdx.x >> 6);
    if (wid >= NGRAPH * 1024) return;
    int t = wid >> 10, j = wid & 1023, lane = threadIdx.x & 63;
    const float* xr = h1 + t * 256;
    const u16* w = parms + P_W_IH + (size_t)j * 256;
    float s = 0.0f;
    #pragma unroll
    for (int q = 0; q < 4; ++q) { int f = lane + 64 * q; s += xr[f] * b2f(w[f]); }
    s = wred(s);
    if (lane == 0) gx[t * 1024 + j] = s + b2f(parms[P_B_IH + j]) + b2f(parms[P_B_HH + j]);
}

// ---------------- sequential LSTM: 512 threads x 2 rows, 3/4 of W_hh pinned ----------
__launch_bounds__(512, 2)
__global__ void k_lstm(const float* __restrict__ gx, const unsigned int* __restrict__ whh4,
                       const u16* __restrict__ parms, void* __restrict__ out,
                       const unsigned int* __restrict__ flag) {
    __shared__ float hs[256];
    __shared__ unsigned int hs2[128];
    __shared__ float gs[1024];
    __shared__ float red[2];
    int tid = threadIdx.x;
    int j0 = tid, j1 = tid + 512;
    u4v wa[24], wb[24];
    #pragma unroll
    for (int q = 0; q < 24; ++q) {
        wa[q] = *(const u4v*)(whh4 + (((size_t)q * 1024) + j0) * 4);
        wb[q] = *(const u4v*)(whh4 + (((size_t)q * 1024) + j1) * 4);
    }
    asm volatile("" : "+v"(wa[0]), "+v"(wa[1]), "+v"(wa[2]), "+v"(wa[3]),
                      "+v"(wa[4]), "+v"(wa[5]), "+v"(wa[6]), "+v"(wa[7]),
                      "+v"(wa[8]), "+v"(wa[9]), "+v"(wa[10]), "+v"(wa[11]),
                      "+v"(wa[12]), "+v"(wa[13]), "+v"(wa[14]), "+v"(wa[15]),
                      "+v"(wa[16]), "+v"(wa[17]), "+v"(wa[18]), "+v"(wa[19]),
                      "+v"(wa[20]), "+v"(wa[21]), "+v"(wa[22]), "+v"(wa[23]));
    asm volatile("" : "+v"(wb[0]), "+v"(wb[1]), "+v"(wb[2]), "+v"(wb[3]),
                      "+v"(wb[4]), "+v"(wb[5]), "+v"(wb[6]), "+v"(wb[7]),
                      "+v"(wb[8]), "+v"(wb[9]), "+v"(wb[10]), "+v"(wb[11]),
                      "+v"(wb[12]), "+v"(wb[13]), "+v"(wb[14]), "+v"(wb[15]),
                      "+v"(wb[16]), "+v"(wb[17]), "+v"(wb[18]), "+v"(wb[19]),
                      "+v"(wb[20]), "+v"(wb[21]), "+v"(wb[22]), "+v"(wb[23]));
    if (tid < 256) hs[tid] = 0.0f;
    if (tid < 128) hs2[tid] = 0u;
    float c = 0.0f;
    __syncthreads();
    for (int t = 0; t < NGRAPH; ++t) {
        float g0 = gx[t * 1024 + j0];
        float g1 = gx[t * 1024 + j1];
        #pragma unroll
        for (int q = 0; q < 24; ++q) {
            #pragma unroll
            for (int cc = 0; cc < 4; ++cc) {
                unsigned h2 = hs2[q * 4 + cc];
                g0 = fdot2u(wa[q][cc], h2, g0);
                g1 = fdot2u(wb[q][cc], h2, g1);
            }
        }
        #pragma unroll 4
        for (int q = 24; q < 32; ++q) {
            u4v v0 = *(const u4v*)(whh4 + (((size_t)q * 1024) + j0) * 4);
            u4v v1 = *(const u4v*)(whh4 + (((size_t)q * 1024) + j1) * 4);
            #pragma unroll
            for (int cc = 0; cc < 4; ++cc) {
                unsigned h2 = hs2[q * 4 + cc];
                g0 = fdot2u(v0[cc], h2, g0);
                g1 = fdot2u(v1[cc], h2, g1);
            }
        }
        gs[j0] = g0;
        gs[j1] = g1;
        __syncthreads();
        if (tid < 256) {
            float gi = 1.0f / (1.0f + expf(-gs[tid]));
            float gf = 1.0f / (1.0f + expf(-gs[256 + tid]));
            float gg = tanhf(gs[512 + tid]);
            float go = 1.0f / (1.0f + expf(-gs[768 + tid]));
            c = gf * c + gi * gg;
            float h = go * tanhf(c);
            hs[tid] = h;
            float ho = __shfl(h, (tid & 63) ^ 1);
            if (!(tid & 1)) hs2[tid >> 1] = packh2(h, ho);
        }
        __syncthreads();
    }
    if (tid < 128) {
        int cls = tid >> 6, lane = tid & 63;
        float s = 0.0f;
        #pragma unroll
        for (int q = 0; q < 4; ++q) {
            int d = lane + 64 * q;
            s += hs[d] * b2f(parms[P_FC2_W + cls * 256 + d]);
        }
        s = wred(s);
        if (lane == 0) red[cls] = s + b2f(parms[P_FC2_B + cls]);
    }
    __syncthreads();
    if (tid == 0) {
        float l0 = red[0], l1 = red[1];
        float m = fmaxf(l0, l1);
        float lse = m + logf(expf(l0 - m) + expf(l1 - m));
        float o0 = l0 - lse, o1 = l1 - lse;
        if (*flag) { ((float*)out)[0] = o0; ((float*)out)[1] = o1; }
        else       { ((u16*)out)[0] = f2b(o0); ((u16*)out)[1] = f2b(o1); }
    }
}

// ---------------- workspace plan (~41 MB) ----------------
struct WS {
    unsigned int* flag; unsigned int* cnt; float* inv; unsigned int* seg; unsigned int* ctr;
    unsigned int* skey; float* sw; unsigned int* bsum;
    u16* Wt2; u16* xc; float* p; float* score;
    unsigned int* topidx; float* topv;
    float* readout; float* h1; float* gx; unsigned int* whh4; u16* parms;
    size_t need;
};
static WS plan(char* base) {
    WS w; size_t off = 0;
    auto take = [&](size_t bytes) -> char* {
        char* p = base + off; off += (bytes + 255) & ~(size_t)255; return p;
    };
    w.flag    = (unsigned int*)take(256);
    w.cnt     = (unsigned int*)take((size_t)NSEG * 4);
    w.inv     = (float*)take((size_t)NSEG * 4);
    w.seg     = (unsigned int*)take((size_t)(NSEG + 1) * 4);
    w.ctr     = (unsigned int*)take((size_t)NSEG * 4);
    w.skey    = (unsigned int*)take((size_t)N_EDGES * 4);
    w.sw      = (float*)take((size_t)N_EDGES * 4);
    w.bsum    = (unsigned int*)take(1024 * 4);
    w.Wt2     = (u16*)take((size_t)3 * 36 * 256 * 64 * 2);
    w.xc      = (u16*)take((size_t)N_NODES * 768 * 2);
    w.p       = (float*)take((size_t)8 * N_NODES * 4);
    w.score   = (float*)take((size_t)N_NODES * 4);
    w.topidx  = (unsigned int*)take((size_t)NGRAPH * 256 * 4);
    w.topv    = (float*)take((size_t)NGRAPH * 256 * 4);
    w.readout = (float*)take((size_t)NGRAPH * 768 * 4);
    w.h1      = (float*)take((size_t)NGRAPH * 256 * 4);
    w.gx      = (float*)take((size_t)NGRAPH * 1024 * 4);
    w.whh4    = (unsigned int*)take((size_t)32 * 1024 * 4 * 4);
    w.parms   = (u16*)take((size_t)P_TOTAL * 2);
    w.need = off;
    return w;
}

extern "C" void kernel_launch(void* const* d_in, const int* in_sizes, int n_in,
                              void* d_out, int out_size, void* d_ws, size_t ws_size,
                              hipStream_t stream) {
    (void)in_sizes; (void)n_in; (void)out_size; (void)ws_size;
    const void* x        = d_in[0];
    const int* edge_index= (const int*)d_in[1];
    const int* edge_attr = (const int*)d_in[2];
    const void* conv_W   = d_in[4];
    const void* conv_root= d_in[5];
    const void* conv_bias= d_in[6];
    const void* pool_W   = d_in[7];
    const void* pool_root= d_in[8];
    const void* pool_bias= d_in[9];
    const void* fc1_W    = d_in[10];
    const void* fc1_b    = d_in[11];
    const void* W_ih     = d_in[12];
    const void* W_hh     = d_in[13];
    const void* b_ih     = d_in[14];
    const void* b_hh     = d_in[15];
    const void* fc2_W    = d_in[16];
    const void* fc2_b    = d_in[17];

    const int* e_src = edge_index;
    const int* e_dst = edge_index + N_EDGES;

    WS w = plan((char*)d_ws);

    k_init<<<(NSEG + 255) / 256, 256, 0, stream>>>(w.flag, w.cnt, w.ctr);
    k_detect1<<<64, 256, 0, stream>>>((const u16*)x, 1 << 18, w.flag);
    k_detect2<<<1, 1, 0, stream>>>(w.flag);

    k_count<<<1250, 256, 0, stream>>>(e_dst, edge_attr, w.cnt);
    k_inv<<<(NSEG + 255) / 256, 256, 0, stream>>>(w.cnt, w.inv, NSEG);
    k_scan1<<<625, 256, 0, stream>>>(w.cnt, w.seg, w.bsum);
    k_scan2<<<1, 1024, 0, stream>>>(w.bsum, 625);
    k_scan3<<<(NSEG + 255) / 256, 256, 0, stream>>>(w.seg, w.bsum);
    k_place<<<1250, 256, 0, stream>>>(e_src, e_dst, edge_attr, w.seg, w.ctr, w.inv,
                                      w.skey, w.sw);

    k_cvt_all<<<(P_TOTAL + 255) / 256, 256, 0, stream>>>(
        conv_bias, pool_W, pool_root, pool_bias, fc1_W, fc1_b,
        W_ih, b_ih, b_hh, fc2_W, fc2_b, w.parms, w.flag);

    k_stage_x<<<20000, 256, 0, stream>>>(x, w.xc, w.flag);
    k_transpose2<<<6912, 256, 0, stream>>>(conv_W, conv_root, w.Wt2, w.flag);
    k_whh4<<<512, 256, 0, stream>>>(W_hh, w.whh4, w.flag);

    for (int l = 0; l < 3; ++l) {
        const u16* xprev = w.xc + (l == 0 ? 512 : (l - 1) * 256);
        const u16* WtL = w.Wt2 + (size_t)l * 36 * 16384;
        const u16* bias = w.parms + P_CONV_BIAS + l * 256;
        k_layer<<<625, 256, 0, stream>>>(w.seg, w.skey, w.sw, xprev, WtL, bias,
                                         w.xc, l * 256);
    }

    k_pool<<<5000, 256, 0, stream>>>(w.xc, w.parms, w.p, w.score);
    k_scatter_pool<<<1250, 256, 0, stream>>>(e_src, e_dst, edge_attr, w.inv, w.p, w.score);
    k_sort<<<NGRAPH, 256, 0, stream>>>(w.score, w.topidx, w.topv);
    k_readout<<<dim3(NGRAPH, 12), 256, 0, stream>>>(w.topidx, w.topv, w.xc, w.readout);
    k_fc1<<<2560, 256, 0, stream>>>(w.readout, w.parms, w.h1);
    k_gx<<<10240, 256, 0, stream>>>(w.h1, w.parms, w.gx);
    k_lstm<<<1, 512, 0, stream>>>(w.gx, w.whh4, w.parms, d_out, w.flag);
}